// Round 7
// baseline (38.286 us; speedup 1.0000x reference)
//
#include <hip/hip_runtime.h>

// 16 x 8 x 512 x 512 fp32; 2x2 grey opening + MSE (scalar out)
#define IMG_H 512
#define IMG_W 512
#define NIMG 128
#define CHUNK 32
#define NCHUNK (IMG_H / CHUNK)            // 16
#define HALVES 2                          // 2 waves of 256 cols per image slab
#define THREADS 256
#define WPB (THREADS / 64)                // 4 waves / block
#define NWAVES (NIMG * NCHUNK * HALVES)   // 4096
#define NBLOCKS (NWAVES / WPB)            // 1024 -> 16 waves/CU (4/SIMD)

// No __launch_bounds__ minimum: R3 showed a (256,4) cap causes scratch spills.
__global__ __launch_bounds__(THREADS)
void opening_mse_kernel(const float* __restrict__ X, float* __restrict__ out) {
    const int lane = threadIdx.x & 63;
    const int gw   = blockIdx.x * WPB + (threadIdx.x >> 6);
    const int n     = gw >> 5;                 // image 0..127
    const int chunk = (gw >> 1) & (NCHUNK - 1);
    const int half  = gw & 1;                  // column half (adjacent waves -> adjacent data)
    const int s = chunk * CHUNK;
    const int e = s + CHUNK;                   // output rows [s, e)
    const int wbase = half << 8;               // 0 or 256
    const float* __restrict__ img = X + (size_t)n * (IMG_H * IMG_W);
    const int c0 = wbase + (lane << 2);        // 4 cols/lane, 256 cols/wave
    const int cl = (wbase > 0) ? wbase - 1 : 0;              // left halo col
    const int cr = (wbase + 256 < IMG_W) ? wbase + 256 : IMG_W - 1; // right halo col
    const bool rightEdge = (wbase + 256 >= IMG_W);
    const int ec = (lane == 0) ? cl : cr;      // per-lane edge address (0/63 matter)
    const int rmax = (e < IMG_H) ? e : (IMG_H - 1);   // overshoot clamp (L1 hit)

    auto ld = [&](int r, float4& a, float& edge) {
        const float* __restrict__ row = img + (size_t)r * IMG_W;
        a = *reinterpret_cast<const float4*>(row + c0);
        edge = row[ec];                        // 2 cache lines/wave, L1/L2 resident
    };

    // h[k] = min(x[c-1], x[c]) for c = c0+k, k=0..4 (h[4] = col c0+4, the
    // dilation's right neighbor). Halos via shuffle; lane 0 / 63 patch from
    // `edge`. Right image edge: h[4]:=h[3] (reflect at col 511).
    auto mkh = [&](const float4& a, float edge, float (&h)[5]) {
        float xl = __shfl_up(a.w, 1, 64);
        if (lane == 0) xl = edge;
        float xr = __shfl_down(a.x, 1, 64);
        if (lane == 63) xr = edge;
        h[0] = fminf(xl, a.x);
        h[1] = fminf(a.x, a.y);
        h[2] = fminf(a.y, a.z);
        h[3] = fminf(a.z, a.w);
        h[4] = fminf(a.w, xr);
        if (rightEdge && lane == 63) h[4] = h[3];
    };

    float hprev[5], hd[4];
    float4 xa;   // x (owned 4 cols) of the row whose opened value we emit next

    {   // prime: h(row s-1 clamped), h(row s), hd[s]
        float4 ta; float te;
        ld(s > 0 ? s - 1 : 0, ta, te);
        mkh(ta, te, hprev);
        float xe;
        ld(s, xa, xe);
        float hcur[5], E[5];
        mkh(xa, xe, hcur);
        #pragma unroll
        for (int k = 0; k < 5; ++k) E[k] = fminf(hprev[k], hcur[k]);
        #pragma unroll
        for (int k = 0; k < 4; ++k) hd[k] = fmaxf(E[k], E[k + 1]);
        #pragma unroll
        for (int k = 0; k < 5; ++k) hprev[k] = hcur[k];
    }

    // depth-4 ring of ROW PAIRS: 8 rows (8 KB/wave) in flight. s+8 <= 488 ok.
    float4 A10, A11, A20, A21, A30, A31, A40, A41;
    float  E10, E11, E20, E21, E30, E31, E40, E41;
    ld(s + 1, A10, E10);  ld(s + 2, A11, E11);
    ld(s + 3, A20, E20);  ld(s + 4, A21, E21);
    ld(s + 5, A30, E30);  ld(s + 6, A31, E31);
    ld(s + 7, A40, E40);  ld(s + 8, A41, E41);

    float acc = 0.0f;
    #pragma unroll 2
    for (int t = 0; t < CHUNK / 2; ++t) {
        const int a0 = s + 1 + 2 * t;
        const int a1 = a0 + 1;

        float4 c0a = A10; float c0e = E10;
        float4 c1a = A11; float c1e = E11;
        A10 = A20; E10 = E20;  A11 = A21; E11 = E21;
        A20 = A30; E20 = E30;  A21 = A31; E21 = E31;
        A30 = A40; E30 = E40;  A31 = A41; E31 = E41;
        int r0 = a0 + 8; r0 = r0 < rmax ? r0 : rmax;
        int r1 = a0 + 9; r1 = r1 < rmax ? r1 : rmax;
        ld(r0, A40, E40);
        ld(r1, A41, E41);

        // ---- row a0 (always < IMG_H)
        float h0[5], hd0[4];
        {
            float E[5];
            mkh(c0a, c0e, h0);
            #pragma unroll
            for (int k = 0; k < 5; ++k) E[k] = fminf(hprev[k], h0[k]);
            #pragma unroll
            for (int k = 0; k < 4; ++k) hd0[k] = fmaxf(E[k], E[k + 1]);
        }
        {   // opened(a0-1) = max(hd, hd0) vs xa
            float d;
            d = xa.x - fmaxf(hd[0], hd0[0]); acc = fmaf(d, d, acc);
            d = xa.y - fmaxf(hd[1], hd0[1]); acc = fmaf(d, d, acc);
            d = xa.z - fmaxf(hd[2], hd0[2]); acc = fmaf(d, d, acc);
            d = xa.w - fmaxf(hd[3], hd0[3]); acc = fmaf(d, d, acc);
        }

        // ---- row a1 (== IMG_H only at the last iteration of the last chunk)
        float hd1[4];
        if (a1 < IMG_H) {
            float h1[5], E[5];
            mkh(c1a, c1e, h1);
            #pragma unroll
            for (int k = 0; k < 5; ++k) E[k] = fminf(h0[k], h1[k]);
            #pragma unroll
            for (int k = 0; k < 4; ++k) hd1[k] = fmaxf(E[k], E[k + 1]);
            #pragma unroll
            for (int k = 0; k < 5; ++k) hprev[k] = h1[k];
        } else {
            #pragma unroll
            for (int k = 0; k < 4; ++k) hd1[k] = hd0[k];   // hd[H] := hd[H-1]
        }
        {   // opened(a1-1) = max(hd0, hd1) vs x(a0) = c0a
            float d;
            d = c0a.x - fmaxf(hd0[0], hd1[0]); acc = fmaf(d, d, acc);
            d = c0a.y - fmaxf(hd0[1], hd1[1]); acc = fmaf(d, d, acc);
            d = c0a.z - fmaxf(hd0[2], hd1[2]); acc = fmaf(d, d, acc);
            d = c0a.w - fmaxf(hd0[3], hd1[3]); acc = fmaf(d, d, acc);
        }

        #pragma unroll
        for (int k = 0; k < 4; ++k) hd[k] = hd1[k];
        xa = c1a;
    }

    // wave shuffle reduce -> LDS across 4 waves -> one atomic per block
    #pragma unroll
    for (int off = 32; off > 0; off >>= 1)
        acc += __shfl_down(acc, off, 64);

    __shared__ float wsum[WPB];
    const int wid = threadIdx.x >> 6;
    if (lane == 0) wsum[wid] = acc;
    __syncthreads();
    if (threadIdx.x == 0) {
        float sblk = wsum[0] + wsum[1] + wsum[2] + wsum[3];
        atomicAdd(out, sblk * (1.0f / 33554432.0f));   // / 2^25 -> mean
    }
}

extern "C" void kernel_launch(void* const* d_in, const int* in_sizes, int n_in,
                              void* d_out, int out_size, void* d_ws, size_t ws_size,
                              hipStream_t stream) {
    const float* X = (const float*)d_in[0];
    float* out = (float*)d_out;
    hipMemsetAsync(out, 0, sizeof(float), stream);
    opening_mse_kernel<<<NBLOCKS, THREADS, 0, stream>>>(X, out);
}

// Round 8
// 34.331 us; speedup vs baseline: 1.1152x; 1.1152x over previous
//
#include <hip/hip_runtime.h>

// 16 x 8 x 512 x 512 fp32; 2x2 grey opening + MSE (scalar out)
// global_load_lds-staged streaming version: per-wave private LDS double
// buffer, no barriers, counted vmcnt gating.
#define IMG_H 512
#define IMG_W 512
#define NIMG 128
#define CHUNK 32
#define NCHUNK (IMG_H / CHUNK)          // 16
#define THREADS 256
#define WPB (THREADS / 64)              // 4 waves / block
#define NBLOCKS (NIMG * NCHUNK / WPB)   // 512

typedef const __attribute__((address_space(1))) void* gvp;
typedef __attribute__((address_space(3))) void* lvp;

__global__ __launch_bounds__(THREADS)
void opening_mse_kernel(const float* __restrict__ X, float* __restrict__ out) {
    // per-wave region: 2 buffers x 4 rows x 512 floats = 16 KB; block = 64 KB
    __shared__ float lds[WPB][2][4][IMG_W];
    __shared__ float wsum[WPB];

    const int lane = threadIdx.x & 63;
    const int wid  = threadIdx.x >> 6;
    const int gw   = blockIdx.x * WPB + wid;
    const int n     = gw >> 4;               // image 0..127
    const int chunk = gw & (NCHUNK - 1);     // 0..15
    const int s = chunk * CHUNK;
    const int e = s + CHUNK;                 // output rows [s, e)
    const float* __restrict__ img = X + (size_t)n * (IMG_H * IMG_W);

    // stage group g = input rows (s-1+4g+j), j=0..3, clamped to [0,511],
    // into lds[wid][g&1][j]. LDS dest is wave-uniform base; HW scatters
    // lane*16B, matching global src row + 16B*lane (guide m97/m104).
    auto stage = [&](int g) {
        const int slot = g & 1;
        #pragma unroll
        for (int j = 0; j < 4; ++j) {
            int r = s - 1 + 4 * g + j;
            r = r < 0 ? 0 : (r > IMG_H - 1 ? IMG_H - 1 : r);
            const float* gp = img + (size_t)r * IMG_W + (lane << 2);
            float* lp = &lds[wid][slot][j][0];
            __builtin_amdgcn_global_load_lds((gvp)gp,         (lvp)lp,         16, 0, 0);
            __builtin_amdgcn_global_load_lds((gvp)(gp + 256), (lvp)(lp + 256), 16, 0, 0);
        }
    };

    auto loadlds = [&](int slot, int j, float4& a, float4& b) {
        const float* Lr = &lds[wid][slot][j][0] + (lane << 3);
        a = *reinterpret_cast<const float4*>(Lr);
        b = *reinterpret_cast<const float4*>(Lr + 4);
    };

    // h[k] = min(x[c-1], x[c]), c = 8*lane+k, k=0..8; h[8] = dilation's right
    // neighbor; lane 63: h[8]=h[7] (reflect at col 511); lane 0: x[-1]=x[0].
    auto mkh = [&](const float4& a, const float4& b, float (&h)[9]) {
        float xl = __shfl_up(b.w, 1, 64);
        if (lane == 0) xl = a.x;
        float xr = __shfl_down(a.x, 1, 64);
        h[0] = fminf(xl, a.x);
        h[1] = fminf(a.x, a.y);
        h[2] = fminf(a.y, a.z);
        h[3] = fminf(a.z, a.w);
        h[4] = fminf(a.w, b.x);
        h[5] = fminf(b.x, b.y);
        h[6] = fminf(b.y, b.z);
        h[7] = fminf(b.z, b.w);
        h[8] = (lane == 63) ? h[7] : fminf(b.w, xr);
    };

    float hprev[9], hd[8];
    float4 xa, xb;       // x of the row whose opened value we emit next
    float acc = 0.0f;

    // process one interior input row from lds[wid][slot][j]; emits one output
    auto step = [&](int slot, int j) {
        float4 a, b;
        float h[9], E[9], hdc[8];
        loadlds(slot, j, a, b);
        mkh(a, b, h);
        #pragma unroll
        for (int k = 0; k < 9; ++k) E[k] = fminf(hprev[k], h[k]);
        #pragma unroll
        for (int k = 0; k < 8; ++k) hdc[k] = fmaxf(E[k], E[k + 1]);
        float d;
        d = xa.x - fmaxf(hd[0], hdc[0]); acc = fmaf(d, d, acc);
        d = xa.y - fmaxf(hd[1], hdc[1]); acc = fmaf(d, d, acc);
        d = xa.z - fmaxf(hd[2], hdc[2]); acc = fmaf(d, d, acc);
        d = xa.w - fmaxf(hd[3], hdc[3]); acc = fmaf(d, d, acc);
        d = xb.x - fmaxf(hd[4], hdc[4]); acc = fmaf(d, d, acc);
        d = xb.y - fmaxf(hd[5], hdc[5]); acc = fmaf(d, d, acc);
        d = xb.z - fmaxf(hd[6], hdc[6]); acc = fmaf(d, d, acc);
        d = xb.w - fmaxf(hd[7], hdc[7]); acc = fmaf(d, d, acc);
        #pragma unroll
        for (int k = 0; k < 8; ++k) hd[k] = hdc[k];
        #pragma unroll
        for (int k = 0; k < 9; ++k) hprev[k] = h[k];
        xa = a; xb = b;
    };

    stage(0);
    stage(1);
    asm volatile("s_waitcnt vmcnt(8)" ::: "memory");   // group 0 landed

    {   // group 0: rows s-1 (prime hprev), s (prime hd,xa), s+1, s+2 (emit)
        float4 a, b;
        float hcur[9], E[9];
        loadlds(0, 0, a, b);
        mkh(a, b, hprev);
        loadlds(0, 1, xa, xb);
        mkh(xa, xb, hcur);
        #pragma unroll
        for (int k = 0; k < 9; ++k) E[k] = fminf(hprev[k], hcur[k]);
        #pragma unroll
        for (int k = 0; k < 8; ++k) hd[k] = fmaxf(E[k], E[k + 1]);
        #pragma unroll
        for (int k = 0; k < 9; ++k) hprev[k] = hcur[k];
        step(0, 2);
        step(0, 3);
    }

    #pragma unroll 2
    for (int g = 1; g <= 7; ++g) {       // groups 1..7: interior rows only
        stage(g + 1);
        asm volatile("s_waitcnt vmcnt(8)" ::: "memory");  // group g landed
        const int slot = g & 1;
        step(slot, 0);
        step(slot, 1);
        step(slot, 2);
        step(slot, 3);
    }

    // group 8 (slot 0): rows s+31 and s+32(=e)
    asm volatile("s_waitcnt vmcnt(0)" ::: "memory");
    step(0, 0);                           // row s+31 -> emit s+30
    if (e < IMG_H) {
        step(0, 1);                       // row e -> emit e-1
    } else {
        // virtual row 512: hd[512] := hd[511]; opened(511) = hd
        float d;
        d = xa.x - hd[0]; acc = fmaf(d, d, acc);
        d = xa.y - hd[1]; acc = fmaf(d, d, acc);
        d = xa.z - hd[2]; acc = fmaf(d, d, acc);
        d = xa.w - hd[3]; acc = fmaf(d, d, acc);
        d = xb.x - hd[4]; acc = fmaf(d, d, acc);
        d = xb.y - hd[5]; acc = fmaf(d, d, acc);
        d = xb.z - hd[6]; acc = fmaf(d, d, acc);
        d = xb.w - hd[7]; acc = fmaf(d, d, acc);
    }

    // wave shuffle reduce -> LDS across 4 waves -> one atomic per block
    #pragma unroll
    for (int off = 32; off > 0; off >>= 1)
        acc += __shfl_down(acc, off, 64);

    if (lane == 0) wsum[wid] = acc;
    __syncthreads();
    if (threadIdx.x == 0) {
        float sblk = wsum[0] + wsum[1] + wsum[2] + wsum[3];
        atomicAdd(out, sblk * (1.0f / 33554432.0f));   // / 2^25 -> mean
    }
}

extern "C" void kernel_launch(void* const* d_in, const int* in_sizes, int n_in,
                              void* d_out, int out_size, void* d_ws, size_t ws_size,
                              hipStream_t stream) {
    const float* X = (const float*)d_in[0];
    float* out = (float*)d_out;
    hipMemsetAsync(out, 0, sizeof(float), stream);
    opening_mse_kernel<<<NBLOCKS, THREADS, 0, stream>>>(X, out);
}